// Round 10
// baseline (443.325 us; speedup 1.0000x reference)
//
#include <hip/hip_runtime.h>
#include <math.h>

// ---------------- workspace layout (float offsets) ----------------
// T tables [r][co]: T1@0(2048) T2@2048(1024) T3@3072(288) T4@3360(256) T5@3616(16)
// S tables [co]:    S1@3632(128) S2@3760(64) S3@3824(32) S4@3856(16) S5@3872(1)
// WT [r][ci4][co][4]: WT1@4096(204800) WT2@208896(131072) WT3@339968(18432)
//                     WT4@358400(8192) WT5@366592(256)  total 366848 floats
#define OFF_T1 0
#define OFF_T2 2048
#define OFF_T3 3072
#define OFF_T4 3360
#define OFF_T5 3616
#define OFF_S1 3632
#define OFF_S2 3760
#define OFF_S3 3824
#define OFF_S4 3856
#define OFF_S5 3872
#define OFF_WT1 4096
#define OFF_WT2 208896
#define OFF_WT3 339968
#define OFF_WT4 358400
#define OFF_WT5 366592

// prep: blocks [0,1417): WT transpose (1 elt/thread)
//       blocks [1417,2325): T[r][co] = sum_ci |w|  (1 WAVE per entry, lane-parallel)
//       blocks [2325,2386): Ssum[co] = sum_{ci,r} |w| (1 WAVE per entry)
__global__ __launch_bounds__(256)
void prep(const float* __restrict__ w1, const float* __restrict__ w2,
          const float* __restrict__ w3, const float* __restrict__ w4,
          const float* __restrict__ w5, float* __restrict__ ws) {
  const int blk = blockIdx.x, tid = threadIdx.x;
  if (blk < 1417) {
    int idx = blk*256 + tid;        // 362752 exactly
    const float* W; int CIN, COUT, KK, e, wtb;
    if (idx < 204800)      { W=w1; CIN=100; COUT=128; KK=16; e=idx;        wtb=OFF_WT1; }
    else if (idx < 335872) { W=w2; CIN=128; COUT=64;  KK=16; e=idx-204800; wtb=OFF_WT2; }
    else if (idx < 354304) { W=w3; CIN=64;  COUT=32;  KK=9;  e=idx-335872; wtb=OFF_WT3; }
    else if (idx < 362496) { W=w4; CIN=32;  COUT=16;  KK=16; e=idx-354304; wtb=OFF_WT4; }
    else                   { W=w5; CIN=16;  COUT=1;   KK=16; e=idx-362496; wtb=OFF_WT5; }
    int ci = e / (COUT*KK); int rem = e % (COUT*KK); int co = rem / KK; int r = rem % KK;
    ws[wtb + ((r*(CIN/4) + (ci>>2))*COUT + co)*4 + (ci&3)] = W[e];
  } else if (blk < 2325) {
    const int wg = (blk-1417)*4 + (tid>>6);    // 0..3631
    const int lane = tid & 63;
    const float* W; int CIN, COUT, KK, tb, local;
    if (wg < 2048)      { W=w1; CIN=100; COUT=128; KK=16; tb=OFF_T1; local=wg; }
    else if (wg < 3072) { W=w2; CIN=128; COUT=64;  KK=16; tb=OFF_T2; local=wg-2048; }
    else if (wg < 3360) { W=w3; CIN=64;  COUT=32;  KK=9;  tb=OFF_T3; local=wg-3072; }
    else if (wg < 3616) { W=w4; CIN=32;  COUT=16;  KK=16; tb=OFF_T4; local=wg-3360; }
    else                { W=w5; CIN=16;  COUT=1;   KK=16; tb=OFF_T5; local=wg-3616; }
    const int r = local / COUT, co = local % COUT;
    float s = 0.f;
    for (int ci = lane; ci < CIN; ci += 64) s += fabsf(W[(ci*COUT + co)*KK + r]);
    #pragma unroll
    for (int off = 1; off < 64; off <<= 1) s += __shfl_xor(s, off, 64);
    if (lane == 0) ws[tb + local] = s;
  } else {
    const int wg = (blk-2325)*4 + (tid>>6);    // 0..243 (valid < 241)
    const int lane = tid & 63;
    if (wg < 241) {
      const float* W; int CIN, COUT, KK, sb, co;
      if (wg < 128)       { W=w1; CIN=100; COUT=128; KK=16; sb=OFF_S1; co=wg; }
      else if (wg < 192)  { W=w2; CIN=128; COUT=64;  KK=16; sb=OFF_S2; co=wg-128; }
      else if (wg < 224)  { W=w3; CIN=64;  COUT=32;  KK=9;  sb=OFF_S3; co=wg-192; }
      else if (wg < 240)  { W=w4; CIN=32;  COUT=16;  KK=16; sb=OFF_S4; co=wg-224; }
      else                { W=w5; CIN=16;  COUT=1;   KK=16; sb=OFF_S5; co=wg-240; }
      const int n = CIN*KK;
      float s = 0.f;
      for (int e = lane; e < n; e += 64)
        s += fabsf(W[(e/KK)*COUT*KK + co*KK + (e % KK)]);
      #pragma unroll
      for (int off = 1; off < 64; off <<= 1) s += __shfl_xor(s, off, 64);
      if (lane == 0) ws[sb + co] = s;
    }
  }
}

// ---- generic adder conv-transpose stage (stride 2, pad 1), block-local.
// X (LDS): [ci4][p*2+b][4]   Y (LDS): [co*2+b][q]   WT (global): [r][ci4][co][4]
// Lane owns an aligned 2x2 output tile; each (kh,kw) matches exactly one
// quadrant's stride-2 parity -> wave-uniform tap loop, no divergence.
// acc starts at Ssum[co] (all K*K taps as structural |w|); each parity-matching
// in-bounds tap corrects by (tap - T[r]):  total = Σ_all T + Σ_real (tap - T).
template<int CIN,int COUT,int K,int HI,int WI,int HO,int WO,int T_L,int CO_LANE,int B_L>
__device__ __forceinline__ void conv(const float* __restrict__ X, float* __restrict__ Y,
                                     const float* __restrict__ WT, const float* __restrict__ Tt,
                                     const float* __restrict__ Ss,
                                     int wave, int lane) {
  constexpr int CIN4 = CIN/4, S = HO*WO, THT = (HO+1)/2, TWT = (WO+1)/2;
  constexpr int NTILES = THT*TWT;
  constexpr int NTG = (NTILES + T_L - 1)/T_L, NCOG = COUT/CO_LANE, NBT = 2/B_L;
  constexpr int NT = NTG*NCOG*NBT;
  const int tl = lane / (CO_LANE*B_L);
  const int lc = (lane / B_L) % CO_LANE;
  const int lb = lane % B_L;
  for (int t = wave; t < NT; t += 16) {
    const int tg  = t % NTG;
    const int r1  = t / NTG;
    const int cog = r1 % NCOG;
    const int tb  = r1 / NCOG;
    const int b   = (B_L == 2) ? lb : tb;
    const int co  = cog*CO_LANE + lc;
    const int tile = tg*T_L + tl;
    const bool tval = (tile < NTILES);
    const int tc  = tval ? tile : 0;
    const int th_ = tc / TWT, tw_ = tc % TWT;

    const float base = Ss[co];
    float acc[4] = {base, base, base, base};   // quadrant (dh*2+dw), static-indexed
    #pragma unroll
    for (int kh = 0; kh < K; ++kh) {
      const int dh = (kh+1)&1;
      const int c1 = (dh + 1 - kh) >> 1;          // PAD=1: ih = th_ + c1 (exact)
      const int ih = th_ + c1, oh = 2*th_ + dh;
      const bool vh = (ih >= 0) && (ih < HI) && (oh < HO);
      const int ihc = min(max(ih, 0), HI-1);
      #pragma unroll
      for (int kw = 0; kw < K; ++kw) {
        const int dw = (kw+1)&1;
        const int c2 = (dw + 1 - kw) >> 1;
        const int iw = tw_ + c2, ow = 2*tw_ + dw;
        const bool vw = (iw >= 0) && (iw < WI) && (ow < WO);
        const int iwc = min(max(iw, 0), WI-1);
        const float maskf = (vh && vw && tval) ? 1.f : 0.f;
        const int r = kh*K + kw;
        const float Tv = Tt[r*COUT + co];
        const int pb = (ihc*WI + iwc)*2 + b;
        const float4* xp = reinterpret_cast<const float4*>(X) + pb;
        const float4* wp = reinterpret_cast<const float4*>(WT) + (size_t)r*CIN4*COUT + co;
        float tap = 0.f;
        #pragma unroll 8
        for (int c = 0; c < CIN4; ++c) {
          const float4 xv = xp[c*(2*HI*WI)];
          const float4 wv = wp[c*COUT];
          tap += fabsf(xv.x - wv.x) + fabsf(xv.y - wv.y)
               + fabsf(xv.z - wv.z) + fabsf(xv.w - wv.w);
        }
        acc[dh*2+dw] += maskf*(tap - Tv);
      }
    }
    #pragma unroll
    for (int dh = 0; dh < 2; ++dh) {
      #pragma unroll
      for (int dw = 0; dw < 2; ++dw) {
        const int oh = 2*th_ + dh, ow = 2*tw_ + dw;
        if (tval && oh < HO && ow < WO)
          Y[(co*2 + b)*S + oh*WO + ow] = acc[dh*2+dw];
      }
    }
  }
}

// ---- instance norm + relu (layers 1-4), block-local (1024 threads).
// Y: [ch][S] (ch = co*2+b); writes next conv input layout [co4][q*2+b][4].
template<int COUT,int S>
__device__ __forceinline__ void norm(const float* __restrict__ Y, float* __restrict__ Xn, int tid) {
  constexpr int NCH = COUT*2, PT = 1024/NCH;   // PT in {4,8,16,32}, divides 64
  const int ch = tid / PT, j = tid % PT;
  const int co = ch >> 1, b = ch & 1;
  const float* yp = Y + ch*S;
  float s = 0.f;
  for (int q = j; q < S; q += PT) s += yp[q];
  #pragma unroll
  for (int off = 1; off < PT; off <<= 1) s += __shfl_xor(s, off, 64);
  const float mu = s * (1.f/S);
  float v = 0.f;
  for (int q = j; q < S; q += PT) { const float d = yp[q] - mu; v += d*d; }
  #pragma unroll
  for (int off = 1; off < PT; off <<= 1) v += __shfl_xor(v, off, 64);
  const float rs = rsqrtf(v * (1.f/S) + 1e-5f);
  for (int q = j; q < S; q += PT) {
    float n = (mu - yp[q]) * rs;            // adder out = -y, norm flips sign
    n = fmaxf(n, 0.f);
    Xn[(((co>>2)*S + q)*2 + b)*4 + (co&3)] = n;
  }
}

// ---- final norm: COUT=1, S=784, tanh, write global out[b][q] (1024 threads)
__device__ __forceinline__ void norm5(const float* __restrict__ Y, float* __restrict__ out,
                                      int tid, int blk, float* __restrict__ scratch) {
  const int b = tid >> 9, j = tid & 511;
  const int wid = tid >> 6, lane = tid & 63;
  const float* yp = Y + b*784;
  float s = 0.f;
  for (int q = j; q < 784; q += 512) s += yp[q];
  #pragma unroll
  for (int off = 1; off < 64; off <<= 1) s += __shfl_xor(s, off, 64);
  if (lane == 0) scratch[wid] = s;
  __syncthreads();
  float mu = 0.f;
  #pragma unroll
  for (int k = 0; k < 8; ++k) mu += scratch[b*8 + k];
  mu *= (1.f/784.f);
  __syncthreads();
  float v = 0.f;
  for (int q = j; q < 784; q += 512) { const float d = yp[q] - mu; v += d*d; }
  #pragma unroll
  for (int off = 1; off < 64; off <<= 1) v += __shfl_xor(v, off, 64);
  if (lane == 0) scratch[wid] = v;
  __syncthreads();
  float vv = 0.f;
  #pragma unroll
  for (int k = 0; k < 8; ++k) vv += scratch[b*8 + k];
  const float rs = rsqrtf(vv * (1.f/784.f) + 1e-5f);
  for (int q = j; q < 784; q += 512) {
    const float n = (mu - yp[q]) * rs;
    const float ax = fabsf(n);
    const float e = __expf(-2.f*ax);
    out[(2*blk + b)*784 + q] = copysignf((1.f - e)/(1.f + e), n);
  }
}

// ---- whole net per b-pair, all activations in LDS, block-local syncs only.
// 1024 threads = 16 waves/CU (4/SIMD) for latency hiding.
__global__ __launch_bounds__(1024)
void fused_main(const float* __restrict__ x, const float* __restrict__ ws,
                float* __restrict__ out) {
  __shared__ float P[6272];      // activation arena (conv inputs)
  __shared__ float Q[6272];      // conv-output arena
  __shared__ float scratch[16];
  const int tid = threadIdx.x;
  const int wave = tid >> 6, lane = tid & 63;
  const int blk = blockIdx.x;

  // load x[2 rows of 100] into L1-input layout [ci4][b][4]
  for (int t = tid; t < 200; t += 1024) {
    const int b = t / 100, ci = t % 100;
    P[((ci>>2)*2 + b)*4 + (ci&3)] = x[(2*blk + b)*100 + ci];
  }
  __syncthreads();
  //   CIN COUT K HI WI HO WO  T_L CO_LANE B_L
  conv<100,128,4, 1, 1, 2, 2,   1, 32, 2>(P, Q, ws+OFF_WT1, ws+OFF_T1, ws+OFF_S1, wave, lane);
  __syncthreads();
  norm<128, 4>(Q, P, tid);
  __syncthreads();
  conv<128, 64,4, 2, 2, 4, 4,   4, 16, 1>(P, Q, ws+OFF_WT2, ws+OFF_T2, ws+OFF_S2, wave, lane);
  __syncthreads();
  norm<64, 16>(Q, P, tid);
  __syncthreads();
  conv< 64, 32,3, 4, 4, 7, 7,  16,  4, 1>(P, Q, ws+OFF_WT3, ws+OFF_T3, ws+OFF_S3, wave, lane);
  __syncthreads();
  norm<32, 49>(Q, P, tid);
  __syncthreads();
  conv< 32, 16,4, 7, 7,14,14,  16,  4, 1>(P, Q, ws+OFF_WT4, ws+OFF_T4, ws+OFF_S4, wave, lane);
  __syncthreads();
  norm<16, 196>(Q, P, tid);
  __syncthreads();
  conv< 16,  1,4,14,14,28,28,  32,  1, 2>(P, Q, ws+OFF_WT5, ws+OFF_T5, ws+OFF_S5, wave, lane);
  __syncthreads();
  norm5(Q, out, tid, blk, scratch);
}

extern "C" void kernel_launch(void* const* d_in, const int* in_sizes, int n_in,
                              void* d_out, int out_size, void* d_ws, size_t ws_size,
                              hipStream_t stream) {
  const float* x  = (const float*)d_in[0];
  const float* w1 = (const float*)d_in[1];
  const float* w2 = (const float*)d_in[2];
  const float* w3 = (const float*)d_in[3];
  const float* w4 = (const float*)d_in[4];
  const float* w5 = (const float*)d_in[5];
  float* ws  = (float*)d_ws;
  float* out = (float*)d_out;

  prep<<<2386, 256, 0, stream>>>(w1, w2, w3, w4, w5, ws);
  fused_main<<<256, 1024, 0, stream>>>(x, ws, out);
}